// Round 11
// baseline (359.460 us; speedup 1.0000x reference)
//
#include <hip/hip_runtime.h>
#include <stdint.h>

typedef unsigned int  uint32;
typedef unsigned short u16;

typedef short bfx8 __attribute__((ext_vector_type(8)));
typedef float f32x4 __attribute__((ext_vector_type(4)));
typedef float f32x2 __attribute__((ext_vector_type(2)));

#define NBP 256          // padded bucket count (N <= 65536)
#define CH  2048         // edges per partition chunk
#define BS  4608         // fixed slots per bucket (mean 4096, sigma~64 -> 8-sigma margin)

// ---------- bf16 helpers ----------
__device__ __forceinline__ float b2f(u16 u) {
    union { uint32 i; float f; } v; v.i = ((uint32)u) << 16; return v.f;
}
__device__ __forceinline__ u16 f2b(float f) {
    union { float f; uint32 i; } v; v.f = f;
    uint32 u = v.i;
    return (u16)((u + 0x7fffu + ((u >> 16) & 1u)) >> 16);   // RNE
}
__device__ __forceinline__ float blo(uint32 u) {
    union { uint32 i; float f; } v; v.i = u << 16; return v.f;
}
__device__ __forceinline__ float bhi(uint32 u) {
    union { uint32 i; float f; } v; v.i = u & 0xffff0000u; return v.f;
}
__device__ __forceinline__ uint32 packbf(float a, float b) {
    return (uint32)f2b(a) | ((uint32)f2b(b) << 16);
}
__device__ __forceinline__ void splitf(float x, u16& h, u16& l) {
    h = f2b(x);
    l = f2b(x - b2f(h));
}

// ---------- partC (+ fused weight split): dual-direction bucket partition ----------
__global__ __launch_bounds__(256) void k_partC_ws(
    const int* __restrict__ row, const int* __restrict__ col, int E, int Gh,
    int* __restrict__ curC, int* __restrict__ curR,
    uint32* __restrict__ partC, uint32* __restrict__ partR,
    const float* __restrict__ W1, const float* __restrict__ W2,
    const float* __restrict__ W3, const float* __restrict__ fcW,
    u16* __restrict__ WTh, u16* __restrict__ WTl, int WTN) {
    __shared__ uint32 stagedC[CH], stagedR[CH];
    __shared__ int hp[NBP], expk[NBP], curp[NBP], runC[NBP], runR[NBP];
    __shared__ int wsum[4];
    int t = threadIdx.x;
    if ((int)blockIdx.x >= Gh) {                 // weight split branch
        int i = ((int)blockIdx.x - Gh) * 256 + t;
        if (i >= WTN) return;
        float w;
        if (i < 3 * 16384) {
            int m = i >> 14, j = i & 16383;      // j = fo*128 + fi
            int fo = j >> 7, fi = j & 127;
            const float* W = (m == 0) ? W1 : (m == 1) ? W2 : W3;
            w = W[fi * 128 + fo];
        } else {
            int j = i - 3 * 16384;
            int fo = j >> 7, fi = j & 127;
            w = fcW[fi * 64 + fo];
        }
        u16 h, l; splitf(w, h, l);
        WTh[i] = h; WTl[i] = l;
        return;
    }
    int lane = t & 63, wid = t >> 6;
    int base = blockIdx.x * CH;
    int n = E - base; if (n > CH) n = CH;

    int er[8], ec[8];
#pragma unroll
    for (int j = 0; j < 8; ++j) {
        int i = t + j * 256;
        if (i < n) { er[j] = row[base + i]; ec[j] = col[base + i]; }
        else er[j] = -1;
    }
    hp[t] = 0;
    __syncthreads();
#pragma unroll
    for (int j = 0; j < 8; ++j) {
        if (er[j] >= 0) {
            atomicAdd(&hp[ec[j] >> 8], 1);
            atomicAdd(&hp[er[j] >> 8], 0x10000);
        }
    }
    __syncthreads();
    int v = hp[t];
    int x = v;
#pragma unroll
    for (int d = 1; d < 64; d <<= 1) {
        int u = __shfl_up(x, d);
        if (lane >= d) x += u;
    }
    if (lane == 63) wsum[wid] = x;
    __syncthreads();
    int add = 0;
    for (int i = 0; i < wid; ++i) add += wsum[i];
    int ex = x + add - v;
    expk[t] = ex;
    curp[t] = ex;
    int vC = v & 0xffff, vR = v >> 16;
    runC[t] = t * BS + (vC ? atomicAdd(&curC[t], vC) : 0);
    runR[t] = t * BS + (vR ? atomicAdd(&curR[t], vR) : 0);
    __syncthreads();
#pragma unroll
    for (int j = 0; j < 8; ++j) {
        if (er[j] >= 0) {
            int cb = ec[j] >> 8, rb = er[j] >> 8;
            int pC = atomicAdd(&curp[cb], 1) & 0xffff;
            stagedC[pC] = ((uint32)ec[j] << 16) | (uint32)er[j];
            int pR = atomicAdd(&curp[rb], 0x10000) >> 16;
            stagedR[pR] = ((uint32)er[j] << 16) | (uint32)ec[j];
        }
    }
    __syncthreads();
    for (int i = t; i < n; i += 256) {
        uint32 pv = stagedC[i];
        int b = pv >> 24;
        partC[runC[b] + (i - (expk[b] & 0xffff))] = pv;
    }
    for (int i = t; i < n; i += 256) {
        uint32 pv = stagedR[i];
        int b = pv >> 24;
        partR[runR[b] + (i - (expk[b] >> 16))] = pv;
    }
}

// ---------- fillD (+ fused gemm0-unscaled) ----------
__global__ __launch_bounds__(256) void k_fillD_g0(
    const uint32* __restrict__ partC, const uint32* __restrict__ partR,
    const int* __restrict__ curC, const int* __restrict__ curR,
    int* __restrict__ off_in, int* __restrict__ end_in,
    int* __restrict__ off_out, int* __restrict__ end_out,
    u16* __restrict__ csr_src, u16* __restrict__ csr_dst,
    float* __restrict__ dinv, int NB, int N,
    const float* __restrict__ A, const u16* __restrict__ WTh,
    const u16* __restrict__ WTl, u16* __restrict__ G) {
    if ((int)blockIdx.x >= 2 * NB) {             // gemm0 branch (unscaled)
        int blk = (int)blockIdx.x - 2 * NB;
        const int lane = threadIdx.x & 63;
        const int q = lane >> 4, l = lane & 15;
        int rbase = blk * 128 + (threadIdx.x >> 6) * 32;
        if (rbase >= N) return;
        int r0 = rbase + l;      if (r0 >= N) r0 = N - 1;
        int r1 = rbase + 16 + l; if (r1 >= N) r1 = N - 1;
        f32x4 acc[2][8];
#pragma unroll
        for (int i = 0; i < 2; ++i)
#pragma unroll
            for (int j = 0; j < 8; ++j) acc[i][j] = (f32x4){0.f, 0.f, 0.f, 0.f};
#pragma unroll
        for (int kc = 0; kc < 4; ++kc) {
            int k0 = kc * 32 + q * 8;
            bfx8 ah0, ah1;
            {
                f32x4 a = *(const f32x4*)(A + (size_t)r0 * 128 + k0);
                f32x4 b = *(const f32x4*)(A + (size_t)r0 * 128 + k0 + 4);
                float xx[8] = {a[0], a[1], a[2], a[3], b[0], b[1], b[2], b[3]};
#pragma unroll
                for (int j = 0; j < 8; ++j) ah0[j] = (short)f2b(xx[j]);
            }
            {
                f32x4 a = *(const f32x4*)(A + (size_t)r1 * 128 + k0);
                f32x4 b = *(const f32x4*)(A + (size_t)r1 * 128 + k0 + 4);
                float xx[8] = {a[0], a[1], a[2], a[3], b[0], b[1], b[2], b[3]};
#pragma unroll
                for (int j = 0; j < 8; ++j) ah1[j] = (short)f2b(xx[j]);
            }
#pragma unroll
            for (int ct = 0; ct < 8; ++ct) {
                bfx8 bh = *(const bfx8*)(WTh + (ct * 16 + l) * 128 + k0);
                bfx8 bl = *(const bfx8*)(WTl + (ct * 16 + l) * 128 + k0);
                acc[0][ct] = __builtin_amdgcn_mfma_f32_16x16x32_bf16(ah0, bh, acc[0][ct], 0, 0, 0);
                acc[0][ct] = __builtin_amdgcn_mfma_f32_16x16x32_bf16(ah0, bl, acc[0][ct], 0, 0, 0);
                acc[1][ct] = __builtin_amdgcn_mfma_f32_16x16x32_bf16(ah1, bh, acc[1][ct], 0, 0, 0);
                acc[1][ct] = __builtin_amdgcn_mfma_f32_16x16x32_bf16(ah1, bl, acc[1][ct], 0, 0, 0);
            }
        }
#pragma unroll
        for (int rs = 0; rs < 2; ++rs) {
#pragma unroll
            for (int rr = 0; rr < 4; ++rr) {
                int rw = rbase + rs * 16 + q * 4 + rr;
                if (rw < N) {
#pragma unroll
                    for (int ct = 0; ct < 8; ++ct)
                        G[(size_t)rw * 128 + ct * 16 + l] = f2b(acc[rs][ct][rr]);
                }
            }
        }
        return;
    }
    int part = ((int)blockIdx.x >= NB) ? 1 : 0;
    int b = (int)blockIdx.x - part * NB;
    const uint32* arr = part ? partR : partC;
    const int* curA   = part ? curR : curC;
    int* offA         = part ? off_out : off_in;
    int* endA         = part ? end_out : end_in;
    u16* csr          = part ? csr_dst : csr_src;
    int t = threadIdx.x;
    int lane = t & 63, wid = t >> 6;
    int base = b * BS, end = base + curA[b];
    __shared__ int cnt[NBP], cur[NBP];
    __shared__ int wsum[4];
    cnt[t] = 0;
    __syncthreads();
    for (int i = base + t; i < end; i += 256)
        atomicAdd(&cnt[(arr[i] >> 16) & 255], 1);
    __syncthreads();
    int v = cnt[t];
    int x = v;
#pragma unroll
    for (int d = 1; d < 64; d <<= 1) {
        int u = __shfl_up(x, d);
        if (lane >= d) x += u;
    }
    if (lane == 63) wsum[wid] = x;
    __syncthreads();
    int add = 0;
    for (int i = 0; i < wid; ++i) add += wsum[i];
    int ex = x + add - v;
    cur[t] = ex;
    int node = (b << 8) + t;
    if (node < N) {
        offA[node] = base + ex;
        endA[node] = base + ex + v;
        if (part == 0) dinv[node] = rsqrtf((float)(v + 1));   // in-degree + self loop
    }
    __syncthreads();
    for (int i = base + t; i < end; i += 256) {
        uint32 pv = arr[i];
        int local = (pv >> 16) & 255;
        int pos = atomicAdd(&cur[local], 1);
        csr[base + pos] = (u16)(pv & 0xffffu);
    }
}

// ---------- agg0: wave-per-node, g unscaled, dinv[src] per neighbor, bf16 out ---------
__global__ __launch_bounds__(256) void k_agg0(
    const uint32* __restrict__ g, const u16* __restrict__ csr,
    const int* __restrict__ off, const int* __restrict__ endo,
    const float* __restrict__ dinv,
    const f32x2* __restrict__ bias, uint32* __restrict__ outH, int n) {
    int w = (blockIdx.x * 256 + threadIdx.x) >> 6;
    if (w >= n) return;
    int lane = threadIdx.x & 63;
    float dc = dinv[w];
    uint32 sv = g[(size_t)w * 64 + lane];
    float s0 = blo(sv) * dc, s1 = bhi(sv) * dc;
    int e = off[w], e1 = endo[w];
    for (; e + 16 <= e1; e += 16) {
        int ix[16];
#pragma unroll
        for (int j = 0; j < 16; ++j) ix[j] = csr[e + j];
        uint32 vv[16];
#pragma unroll
        for (int j = 0; j < 16; ++j) vv[j] = g[(size_t)ix[j] * 64 + lane];
        float dm[16];
#pragma unroll
        for (int j = 0; j < 16; ++j) dm[j] = dinv[ix[j]];
#pragma unroll
        for (int j = 0; j < 16; ++j) {
            s0 = fmaf(blo(vv[j]), dm[j], s0);
            s1 = fmaf(bhi(vv[j]), dm[j], s1);
        }
    }
    for (; e < e1; ++e) {
        int ix = csr[e];
        uint32 v = g[(size_t)ix * 64 + lane];
        float dm = dinv[ix];
        s0 = fmaf(blo(v), dm, s0);
        s1 = fmaf(bhi(v), dm, s1);
    }
    f32x2 bb = bias[lane];
    float o0 = fmaxf(fmaf(s0, dc, bb[0]), 0.f);
    float o1 = fmaxf(fmaf(s1, dc, bb[1]), 0.f);
    outH[(size_t)w * 64 + lane] = packbf(o0, o1);
}

// ---------- shared gather helper (pre-scaled sum over csr[e..e1)) ----------
__device__ __forceinline__ void gather_sum(
    const uint32* __restrict__ g, const u16* __restrict__ csr,
    int e, int e1, int lane, float& s0, float& s1) {
    for (; e + 16 <= e1; e += 16) {
        int ix[16];
#pragma unroll
        for (int j = 0; j < 16; ++j) ix[j] = csr[e + j];
        uint32 vv[16];
#pragma unroll
        for (int j = 0; j < 16; ++j) vv[j] = g[(size_t)ix[j] * 64 + lane];
#pragma unroll
        for (int j = 0; j < 16; ++j) { s0 += blo(vv[j]); s1 += bhi(vv[j]); }
    }
    for (; e + 4 <= e1; e += 4) {
        int ix[4];
#pragma unroll
        for (int j = 0; j < 4; ++j) ix[j] = csr[e + j];
        uint32 vv[4];
#pragma unroll
        for (int j = 0; j < 4; ++j) vv[j] = g[(size_t)ix[j] * 64 + lane];
#pragma unroll
        for (int j = 0; j < 4; ++j) { s0 += blo(vv[j]); s1 += bhi(vv[j]); }
    }
    for (; e < e1; ++e) {
        uint32 v = g[(size_t)csr[e] * 64 + lane];
        s0 += blo(v); s1 += bhi(v);
    }
}

// ---------- GEMM-from-LDS-tile phase: 16 rows x 128 cols, per-wave 2 col-tiles --------
__device__ __forceinline__ void tile_gemm128(
    const u16* __restrict__ tile,                // 16 x 136 bf16, padded
    const u16* __restrict__ WTh, const u16* __restrict__ WTl,
    const float* __restrict__ dinv, u16* __restrict__ G, int nbase, int N,
    int wv, int lane) {
    const int q = lane >> 4, l = lane & 15;
    f32x4 acc[2];
    acc[0] = (f32x4){0.f, 0.f, 0.f, 0.f};
    acc[1] = (f32x4){0.f, 0.f, 0.f, 0.f};
#pragma unroll
    for (int kc = 0; kc < 4; ++kc) {
        bfx8 a = *(const bfx8*)(tile + l * 136 + kc * 32 + q * 8);
#pragma unroll
        for (int c = 0; c < 2; ++c) {
            int ct = 2 * wv + c;
            bfx8 bh = *(const bfx8*)(WTh + (ct * 16 + l) * 128 + kc * 32 + q * 8);
            bfx8 bl = *(const bfx8*)(WTl + (ct * 16 + l) * 128 + kc * 32 + q * 8);
            acc[c] = __builtin_amdgcn_mfma_f32_16x16x32_bf16(a, bh, acc[c], 0, 0, 0);
            acc[c] = __builtin_amdgcn_mfma_f32_16x16x32_bf16(a, bl, acc[c], 0, 0, 0);
        }
    }
#pragma unroll
    for (int rr = 0; rr < 4; ++rr) {
        int rw = nbase + q * 4 + rr;
        if (rw < N) {
            float dv = dinv[rw];
#pragma unroll
            for (int c = 0; c < 2; ++c)
                G[(size_t)rw * 128 + (2 * wv + c) * 16 + l] = f2b(acc[c][rr] * dv);
        }
    }
}

// ---------- fused: neighbor-mean (out-CSR) -> h0 + gemm1 (prescaled) ----------
__global__ __launch_bounds__(256) void k_meangemm1(
    const uint32* __restrict__ t0, const u16* __restrict__ csr,
    const int* __restrict__ off, const int* __restrict__ endo,
    uint32* __restrict__ h0, const u16* __restrict__ WTh, const u16* __restrict__ WTl,
    const float* __restrict__ dinv, u16* __restrict__ G, int N) {
    __shared__ u16 tile[16 * 136];
    int t = threadIdx.x;
    int wv = t >> 6, lane = t & 63;
    int nbase = blockIdx.x * 16;
#pragma unroll
    for (int k = 0; k < 4; ++k) {
        int r = nbase + wv * 4 + k;
        bool valid = (r < N);
        int rc = valid ? r : N - 1;
        int e = off[rc], e1 = endo[rc];
        int deg = e1 - e;
        float s0 = 0.f, s1 = 0.f;
        gather_sum(t0, csr, e, e1, lane, s0, s1);
        float o0, o1;
        if (deg > 0) {
            float inv = 1.f / (float)deg;
            o0 = s0 * inv; o1 = s1 * inv;
        } else {
            uint32 sv = t0[(size_t)rc * 64 + lane];
            o0 = blo(sv); o1 = bhi(sv);
        }
        uint32 pk = packbf(o0, o1);
        ((uint32*)tile)[(wv * 4 + k) * 68 + lane] = pk;
        if (valid) h0[(size_t)r * 64 + lane] = pk;
    }
    __syncthreads();
    tile_gemm128(tile, WTh, WTl, dinv, G, nbase, N, wv, lane);
}

// ---------- fused: GCN agg (in-CSR, prescaled) -> h1 + gemm2 (prescaled) ----------
__global__ __launch_bounds__(256) void k_agggemm2(
    const uint32* __restrict__ gA, const u16* __restrict__ csr,
    const int* __restrict__ off, const int* __restrict__ endo,
    const float* __restrict__ dinv, const f32x2* __restrict__ bias,
    uint32* __restrict__ h1, const u16* __restrict__ WTh, const u16* __restrict__ WTl,
    u16* __restrict__ G, int N) {
    __shared__ u16 tile[16 * 136];
    int t = threadIdx.x;
    int wv = t >> 6, lane = t & 63;
    int nbase = blockIdx.x * 16;
    f32x2 bb = bias[lane];
#pragma unroll
    for (int k = 0; k < 4; ++k) {
        int r = nbase + wv * 4 + k;
        bool valid = (r < N);
        int rc = valid ? r : N - 1;
        uint32 sv = gA[(size_t)rc * 64 + lane];
        float s0 = blo(sv), s1 = bhi(sv);
        gather_sum(gA, csr, off[rc], endo[rc], lane, s0, s1);
        float dc = dinv[rc];
        float o0 = fmaxf(fmaf(s0, dc, bb[0]), 0.f);
        float o1 = fmaxf(fmaf(s1, dc, bb[1]), 0.f);
        uint32 pk = packbf(o0, o1);
        ((uint32*)tile)[(wv * 4 + k) * 68 + lane] = pk;
        if (valid) h1[(size_t)r * 64 + lane] = pk;
    }
    __syncthreads();
    tile_gemm128(tile, WTh, WTl, dinv, G, nbase, N, wv, lane);
}

// ---------- fused: GCN agg (layer2) -> JK combine -> final 128x64 GEMM -> out ---------
__global__ __launch_bounds__(256) void k_aggfinal(
    const uint32* __restrict__ gB, const u16* __restrict__ csr,
    const int* __restrict__ off, const int* __restrict__ endo,
    const float* __restrict__ dinv, const f32x2* __restrict__ bias,
    const uint32* __restrict__ h0, const uint32* __restrict__ h1,
    const float* __restrict__ jkw,
    const u16* __restrict__ fcWTh, const u16* __restrict__ fcWTl,
    const float* __restrict__ fcb, float* __restrict__ out, int N) {
    __shared__ u16 tile[16 * 136];
    float a0 = jkw[0], a1 = jkw[1], a2 = jkw[2];
    float mx = fmaxf(a0, fmaxf(a1, a2));
    float e0 = expf(a0 - mx), e1x = expf(a1 - mx), e2 = expf(a2 - mx);
    float inv = 1.f / (e0 + e1x + e2);
    float w0 = e0 * inv, w1 = e1x * inv, w2 = e2 * inv;

    int t = threadIdx.x;
    int wv = t >> 6, lane = t & 63;
    int nbase = blockIdx.x * 16;
    f32x2 bb = bias[lane];
#pragma unroll
    for (int k = 0; k < 4; ++k) {
        int r = nbase + wv * 4 + k;
        int rc = (r < N) ? r : N - 1;
        uint32 sv = gB[(size_t)rc * 64 + lane];
        float s0 = blo(sv), s1 = bhi(sv);
        gather_sum(gB, csr, off[rc], endo[rc], lane, s0, s1);
        float dc = dinv[rc];
        float o0 = fmaxf(fmaf(s0, dc, bb[0]), 0.f);   // h2 row element pair
        float o1 = fmaxf(fmaf(s1, dc, bb[1]), 0.f);
        uint32 v0 = h0[(size_t)rc * 64 + lane];
        uint32 v1 = h1[(size_t)rc * 64 + lane];
        float c0 = w0 * blo(v0) + w1 * blo(v1) + w2 * o0;
        float c1 = w0 * bhi(v0) + w1 * bhi(v1) + w2 * o1;
        ((uint32*)tile)[(wv * 4 + k) * 68 + lane] = packbf(c0, c1);
    }
    __syncthreads();
    // GEMM: 16 x 128 @ 128 x 64; wave wv computes cols [wv*16, wv*16+16)
    const int q = lane >> 4, l = lane & 15;
    f32x4 acc = (f32x4){0.f, 0.f, 0.f, 0.f};
#pragma unroll
    for (int kc = 0; kc < 4; ++kc) {
        bfx8 a = *(const bfx8*)(tile + l * 136 + kc * 32 + q * 8);
        bfx8 bh = *(const bfx8*)(fcWTh + (wv * 16 + l) * 128 + kc * 32 + q * 8);
        bfx8 bl = *(const bfx8*)(fcWTl + (wv * 16 + l) * 128 + kc * 32 + q * 8);
        acc = __builtin_amdgcn_mfma_f32_16x16x32_bf16(a, bh, acc, 0, 0, 0);
        acc = __builtin_amdgcn_mfma_f32_16x16x32_bf16(a, bl, acc, 0, 0, 0);
    }
    float fb = fcb[wv * 16 + l];
#pragma unroll
    for (int rr = 0; rr < 4; ++rr) {
        int rw = nbase + q * 4 + rr;
        if (rw < N)
            out[(size_t)rw * 64 + wv * 16 + l] = acc[rr] + fb;
    }
}

extern "C" void kernel_launch(void* const* d_in, const int* in_sizes, int n_in,
                              void* d_out, int out_size, void* d_ws, size_t ws_size,
                              hipStream_t stream) {
    const int N = in_sizes[0] / 128;   // 50000
    const int E = in_sizes[1] / 2;     // 800000
    const int NB = (N + 255) >> 8;     // 196 buckets

    const float* x    = (const float*)d_in[0];
    const int* row    = (const int*)d_in[1];
    const int* col    = row + E;
    const float* W1   = (const float*)d_in[2];
    const float* b1   = (const float*)d_in[3];
    const float* W2   = (const float*)d_in[4];
    const float* b2   = (const float*)d_in[5];
    const float* W3   = (const float*)d_in[6];
    const float* b3   = (const float*)d_in[7];
    const float* jkw  = (const float*)d_in[8];
    const float* fcW  = (const float*)d_in[9];
    const float* fcb  = (const float*)d_in[10];
    float* outp       = (float*)d_out;

    char* ws = (char*)d_ws;
    size_t off = 0;
    auto alloc = [&](size_t bytes) -> char* {
        char* p = ws + off;
        off += (bytes + 255) & ~(size_t)255;
        return p;
    };
    int* curC   = (int*)alloc((size_t)2 * NBP * sizeof(int));  // zero-init (memset)
    int* curR   = curC + NBP;
    int* off_in  = (int*)alloc((size_t)N * sizeof(int));
    int* end_in  = (int*)alloc((size_t)N * sizeof(int));
    int* off_out = (int*)alloc((size_t)N * sizeof(int));
    int* end_out = (int*)alloc((size_t)N * sizeof(int));
    uint32* partC = (uint32*)alloc((size_t)NBP * BS * sizeof(uint32));
    uint32* partR = (uint32*)alloc((size_t)NBP * BS * sizeof(uint32));
    u16* csr_src = (u16*)alloc((size_t)NBP * BS * sizeof(u16));
    u16* csr_dst = (u16*)alloc((size_t)NBP * BS * sizeof(u16));
    float* dinv  = (float*)alloc((size_t)N * sizeof(float));
    const int WTN = 3 * 16384 + 8192;
    u16* WTh = (u16*)alloc((size_t)WTN * sizeof(u16));
    u16* WTl = (u16*)alloc((size_t)WTN * sizeof(u16));
    size_t FB = (size_t)N * 128 * sizeof(u16);
    u16* g0 = (u16*)alloc(FB);   // gemm0 out (unscaled)
    u16* t0 = (u16*)alloc(FB);   // agg0 out
    u16* h0 = (u16*)alloc(FB);
    u16* h1 = (u16*)alloc(FB);
    u16* gA = (u16*)alloc(FB);   // gemm1 out (prescaled)
    u16* gB = (u16*)alloc(FB);   // gemm2 out (prescaled)

    hipMemsetAsync(curC, 0, (size_t)2 * NBP * sizeof(int), stream);

    const int B = 256;
    int Gh = (E + CH - 1) / CH;
    int Gg = (N + 127) / 128;
    int Gwt = (WTN + B - 1) / B;
    int Gf = (N + 15) / 16;            // fused gather+gemm blocks (16 nodes each)

    k_partC_ws<<<Gh + Gwt, B, 0, stream>>>(row, col, E, Gh, curC, curR, partC, partR,
                                           W1, W2, W3, fcW, WTh, WTl, WTN);
    k_fillD_g0<<<2 * NB + Gg, B, 0, stream>>>(partC, partR, curC, curR,
                                              off_in, end_in, off_out, end_out,
                                              csr_src, csr_dst, dinv, NB, N,
                                              x, WTh, WTl, g0);
    int aggG = (N + 3) / 4;
    k_agg0<<<aggG, B, 0, stream>>>((const uint32*)g0, csr_src, off_in, end_in, dinv,
                                   (const f32x2*)b1, (uint32*)t0, N);
    k_meangemm1<<<Gf, B, 0, stream>>>((const uint32*)t0, csr_dst, off_out, end_out,
                                      (uint32*)h0, WTh + 16384, WTl + 16384,
                                      dinv, gA, N);
    k_agggemm2<<<Gf, B, 0, stream>>>((const uint32*)gA, csr_src, off_in, end_in,
                                     dinv, (const f32x2*)b2, (uint32*)h1,
                                     WTh + 2 * 16384, WTl + 2 * 16384, gB, N);
    k_aggfinal<<<Gf, B, 0, stream>>>((const uint32*)gB, csr_src, off_in, end_in,
                                     dinv, (const f32x2*)b3,
                                     (const uint32*)h0, (const uint32*)h1, jkw,
                                     WTh + 3 * 16384, WTl + 3 * 16384, fcb, outp, N);
}

// Round 12
// 335.394 us; speedup vs baseline: 1.0718x; 1.0718x over previous
//
#include <hip/hip_runtime.h>
#include <stdint.h>

typedef unsigned int  uint32;
typedef unsigned short u16;

typedef short bfx8 __attribute__((ext_vector_type(8)));
typedef float f32x4 __attribute__((ext_vector_type(4)));
typedef float f32x2 __attribute__((ext_vector_type(2)));

#define NBP 256          // padded bucket count (N <= 65536)
#define CH  2048         // edges per partition chunk
#define BS  4608         // fixed slots per bucket (mean 4096, sigma~64 -> 8-sigma margin)

// ---------- bf16 helpers ----------
__device__ __forceinline__ float b2f(u16 u) {
    union { uint32 i; float f; } v; v.i = ((uint32)u) << 16; return v.f;
}
__device__ __forceinline__ u16 f2b(float f) {
    union { float f; uint32 i; } v; v.f = f;
    uint32 u = v.i;
    return (u16)((u + 0x7fffu + ((u >> 16) & 1u)) >> 16);   // RNE
}
__device__ __forceinline__ float blo(uint32 u) {
    union { uint32 i; float f; } v; v.i = u << 16; return v.f;
}
__device__ __forceinline__ float bhi(uint32 u) {
    union { uint32 i; float f; } v; v.i = u & 0xffff0000u; return v.f;
}
__device__ __forceinline__ uint32 packbf(float a, float b) {
    return (uint32)f2b(a) | ((uint32)f2b(b) << 16);
}
__device__ __forceinline__ void splitf(float x, u16& h, u16& l) {
    h = f2b(x);
    l = f2b(x - b2f(h));
}

// ---------- init: block 0 sets bucket cursors; other blocks split weights ----------
__global__ __launch_bounds__(256) void k_init(
    int* __restrict__ curC, int* __restrict__ curR,
    const float* __restrict__ W1, const float* __restrict__ W2,
    const float* __restrict__ W3, const float* __restrict__ fcW,
    u16* __restrict__ WTh, u16* __restrict__ WTl, int WTN) {
    int t = threadIdx.x;
    if (blockIdx.x == 0) {
        curC[t] = t * BS;
        curR[t] = t * BS;
        return;
    }
    int i = ((int)blockIdx.x - 1) * 256 + t;
    if (i >= WTN) return;
    float w;
    if (i < 3 * 16384) {
        int m = i >> 14, j = i & 16383;     // j = fo*128 + fi
        int fo = j >> 7, fi = j & 127;
        const float* W = (m == 0) ? W1 : (m == 1) ? W2 : W3;
        w = W[fi * 128 + fo];
    } else {
        int j = i - 3 * 16384;
        int fo = j >> 7, fi = j & 127;
        w = fcW[fi * 64 + fo];
    }
    u16 h, l; splitf(w, h, l);
    WTh[i] = h; WTl[i] = l;
}

// ---------- pass C: dual-direction bucket partition into fixed-stride regions ---------
__global__ __launch_bounds__(256) void k_partC(
    const int* __restrict__ row, const int* __restrict__ col, int E,
    int* __restrict__ curC, int* __restrict__ curR,
    uint32* __restrict__ partC, uint32* __restrict__ partR) {
    __shared__ uint32 stagedC[CH], stagedR[CH];
    __shared__ int hp[NBP], expk[NBP], curp[NBP], runC[NBP], runR[NBP];
    __shared__ int wsum[4];
    int t = threadIdx.x;
    int lane = t & 63, wid = t >> 6;
    int base = blockIdx.x * CH;
    int n = E - base; if (n > CH) n = CH;

    int er[8], ec[8];
#pragma unroll
    for (int j = 0; j < 8; ++j) {
        int i = t + j * 256;
        if (i < n) { er[j] = row[base + i]; ec[j] = col[base + i]; }
        else er[j] = -1;
    }
    hp[t] = 0;
    __syncthreads();
#pragma unroll
    for (int j = 0; j < 8; ++j) {
        if (er[j] >= 0) {
            atomicAdd(&hp[ec[j] >> 8], 1);
            atomicAdd(&hp[er[j] >> 8], 0x10000);
        }
    }
    __syncthreads();
    int v = hp[t];
    int x = v;
#pragma unroll
    for (int d = 1; d < 64; d <<= 1) {
        int u = __shfl_up(x, d);
        if (lane >= d) x += u;
    }
    if (lane == 63) wsum[wid] = x;
    __syncthreads();
    int add = 0;
    for (int i = 0; i < wid; ++i) add += wsum[i];
    int ex = x + add - v;
    expk[t] = ex;
    curp[t] = ex;
    int vC = v & 0xffff, vR = v >> 16;
    runC[t] = vC ? atomicAdd(&curC[t], vC) : 0;
    runR[t] = vR ? atomicAdd(&curR[t], vR) : 0;
    __syncthreads();
#pragma unroll
    for (int j = 0; j < 8; ++j) {
        if (er[j] >= 0) {
            int cb = ec[j] >> 8, rb = er[j] >> 8;
            int pC = atomicAdd(&curp[cb], 1) & 0xffff;
            stagedC[pC] = ((uint32)ec[j] << 16) | (uint32)er[j];
            int pR = atomicAdd(&curp[rb], 0x10000) >> 16;
            stagedR[pR] = ((uint32)er[j] << 16) | (uint32)ec[j];
        }
    }
    __syncthreads();
    for (int i = t; i < n; i += 256) {
        uint32 pv = stagedC[i];
        int b = pv >> 24;
        partC[runC[b] + (i - (expk[b] & 0xffff))] = pv;
    }
    for (int i = t; i < n; i += 256) {
        uint32 pv = stagedR[i];
        int b = pv >> 24;
        partR[runR[b] + (i - (expk[b] >> 16))] = pv;
    }
}

// ---------- pass D: per-bucket CSR fill + per-node (start,end) + dinv ----------
__global__ __launch_bounds__(256) void k_fillD(
    const uint32* __restrict__ partC, const uint32* __restrict__ partR,
    const int* __restrict__ curC, const int* __restrict__ curR,
    int* __restrict__ off_in, int* __restrict__ end_in,
    int* __restrict__ off_out, int* __restrict__ end_out,
    u16* __restrict__ csr_src, u16* __restrict__ csr_dst,
    float* __restrict__ dinv, int NB, int N) {
    int part = ((int)blockIdx.x >= NB) ? 1 : 0;
    int b = (int)blockIdx.x - part * NB;
    const uint32* arr = part ? partR : partC;
    const int* curA   = part ? curR : curC;
    int* offA         = part ? off_out : off_in;
    int* endA         = part ? end_out : end_in;
    u16* csr          = part ? csr_dst : csr_src;
    int t = threadIdx.x;
    int lane = t & 63, wid = t >> 6;
    int base = b * BS, end = curA[b];
    __shared__ int cnt[NBP], cur[NBP];
    __shared__ int wsum[4];
    cnt[t] = 0;
    __syncthreads();
    for (int i = base + t; i < end; i += 256)
        atomicAdd(&cnt[(arr[i] >> 16) & 255], 1);
    __syncthreads();
    int v = cnt[t];
    int x = v;
#pragma unroll
    for (int d = 1; d < 64; d <<= 1) {
        int u = __shfl_up(x, d);
        if (lane >= d) x += u;
    }
    if (lane == 63) wsum[wid] = x;
    __syncthreads();
    int add = 0;
    for (int i = 0; i < wid; ++i) add += wsum[i];
    int ex = x + add - v;
    cur[t] = ex;
    int node = (b << 8) + t;
    if (node < N) {
        offA[node] = base + ex;
        endA[node] = base + ex + v;
        if (part == 0) dinv[node] = rsqrtf((float)(v + 1));   // in-degree + self loop
    }
    __syncthreads();
    for (int i = base + t; i < end; i += 256) {
        uint32 pv = arr[i];
        int local = (pv >> 16) & 255;
        int pos = atomicAdd(&cur[local], 1);
        csr[base + pos] = (u16)(pv & 0xffffu);
    }
}

// ---------- gemm0 (fp32 A, single-plane bf16 cast): G = (A @ W) * dinv, bf16 out ------
__global__ __launch_bounds__(256) void k_gemm0(
    const float* __restrict__ A, const u16* __restrict__ WTh, const u16* __restrict__ WTl,
    const float* __restrict__ dinv, u16* __restrict__ G, int M) {
    const int lane = threadIdx.x & 63;
    const int q = lane >> 4, l = lane & 15;
    int rbase = blockIdx.x * 128 + (threadIdx.x >> 6) * 32;
    if (rbase >= M) return;
    int r0 = rbase + l;      if (r0 >= M) r0 = M - 1;
    int r1 = rbase + 16 + l; if (r1 >= M) r1 = M - 1;

    f32x4 acc[2][8];
#pragma unroll
    for (int i = 0; i < 2; ++i)
#pragma unroll
        for (int j = 0; j < 8; ++j) acc[i][j] = (f32x4){0.f, 0.f, 0.f, 0.f};

#pragma unroll
    for (int kc = 0; kc < 4; ++kc) {
        int k0 = kc * 32 + q * 8;
        bfx8 ah0, ah1;
        {
            f32x4 a = *(const f32x4*)(A + (size_t)r0 * 128 + k0);
            f32x4 b = *(const f32x4*)(A + (size_t)r0 * 128 + k0 + 4);
            float xx[8] = {a[0], a[1], a[2], a[3], b[0], b[1], b[2], b[3]};
#pragma unroll
            for (int j = 0; j < 8; ++j) ah0[j] = (short)f2b(xx[j]);
        }
        {
            f32x4 a = *(const f32x4*)(A + (size_t)r1 * 128 + k0);
            f32x4 b = *(const f32x4*)(A + (size_t)r1 * 128 + k0 + 4);
            float xx[8] = {a[0], a[1], a[2], a[3], b[0], b[1], b[2], b[3]};
#pragma unroll
            for (int j = 0; j < 8; ++j) ah1[j] = (short)f2b(xx[j]);
        }
#pragma unroll
        for (int ct = 0; ct < 8; ++ct) {
            bfx8 bh = *(const bfx8*)(WTh + (ct * 16 + l) * 128 + k0);
            bfx8 bl = *(const bfx8*)(WTl + (ct * 16 + l) * 128 + k0);
            acc[0][ct] = __builtin_amdgcn_mfma_f32_16x16x32_bf16(ah0, bh, acc[0][ct], 0, 0, 0);
            acc[0][ct] = __builtin_amdgcn_mfma_f32_16x16x32_bf16(ah0, bl, acc[0][ct], 0, 0, 0);
            acc[1][ct] = __builtin_amdgcn_mfma_f32_16x16x32_bf16(ah1, bh, acc[1][ct], 0, 0, 0);
            acc[1][ct] = __builtin_amdgcn_mfma_f32_16x16x32_bf16(ah1, bl, acc[1][ct], 0, 0, 0);
        }
    }
#pragma unroll
    for (int rs = 0; rs < 2; ++rs) {
#pragma unroll
        for (int rr = 0; rr < 4; ++rr) {
            int rw = rbase + rs * 16 + q * 4 + rr;
            if (rw < M) {
                float dv = dinv[rw];
#pragma unroll
                for (int ct = 0; ct < 8; ++ct)
                    G[(size_t)rw * 128 + ct * 16 + l] = f2b(acc[rs][ct][rr] * dv);
            }
        }
    }
}

// ---------- gemm, single bf16-plane A: G = (A @ W) * dinv, bf16 out ----------
__global__ __launch_bounds__(256) void k_gemm1p(
    const u16* __restrict__ Ah,
    const u16* __restrict__ WTh, const u16* __restrict__ WTl,
    const float* __restrict__ dinv, u16* __restrict__ G, int M) {
    const int lane = threadIdx.x & 63;
    const int q = lane >> 4, l = lane & 15;
    int rbase = blockIdx.x * 128 + (threadIdx.x >> 6) * 32;
    if (rbase >= M) return;
    int r0 = rbase + l;      if (r0 >= M) r0 = M - 1;
    int r1 = rbase + 16 + l; if (r1 >= M) r1 = M - 1;

    f32x4 acc[2][8];
#pragma unroll
    for (int i = 0; i < 2; ++i)
#pragma unroll
        for (int j = 0; j < 8; ++j) acc[i][j] = (f32x4){0.f, 0.f, 0.f, 0.f};

#pragma unroll
    for (int kc = 0; kc < 4; ++kc) {
        int k0 = kc * 32 + q * 8;
        bfx8 ah0 = *(const bfx8*)(Ah + (size_t)r0 * 128 + k0);
        bfx8 ah1 = *(const bfx8*)(Ah + (size_t)r1 * 128 + k0);
#pragma unroll
        for (int ct = 0; ct < 8; ++ct) {
            bfx8 bh = *(const bfx8*)(WTh + (ct * 16 + l) * 128 + k0);
            bfx8 bl = *(const bfx8*)(WTl + (ct * 16 + l) * 128 + k0);
            acc[0][ct] = __builtin_amdgcn_mfma_f32_16x16x32_bf16(ah0, bh, acc[0][ct], 0, 0, 0);
            acc[0][ct] = __builtin_amdgcn_mfma_f32_16x16x32_bf16(ah0, bl, acc[0][ct], 0, 0, 0);
            acc[1][ct] = __builtin_amdgcn_mfma_f32_16x16x32_bf16(ah1, bh, acc[1][ct], 0, 0, 0);
            acc[1][ct] = __builtin_amdgcn_mfma_f32_16x16x32_bf16(ah1, bl, acc[1][ct], 0, 0, 0);
        }
    }
#pragma unroll
    for (int rs = 0; rs < 2; ++rs) {
#pragma unroll
        for (int rr = 0; rr < 4; ++rr) {
            int rw = rbase + rs * 16 + q * 4 + rr;
            if (rw < M) {
                float dv = dinv[rw];
#pragma unroll
                for (int ct = 0; ct < 8; ++ct)
                    G[(size_t)rw * 128 + ct * 16 + l] = f2b(acc[rs][ct][rr] * dv);
            }
        }
    }
}

// ---------- GCN aggregate, wave-per-node, 16-unroll (g pre-scaled) ----------
// out[c] = relu(dinv[c]*(g[c] + sum g[src]) + b), bf16 out
__global__ __launch_bounds__(256) void k_agg(
    const uint32* __restrict__ g, const u16* __restrict__ csr,
    const int* __restrict__ off, const int* __restrict__ endo,
    const float* __restrict__ dinv,
    const f32x2* __restrict__ bias, uint32* __restrict__ outH, int n) {
    int w = (blockIdx.x * 256 + threadIdx.x) >> 6;
    if (w >= n) return;
    int lane = threadIdx.x & 63;
    uint32 sv = g[(size_t)w * 64 + lane];
    float s0 = blo(sv), s1 = bhi(sv);
    int e = off[w], e1 = endo[w];
    for (; e + 16 <= e1; e += 16) {
        int ix[16];
#pragma unroll
        for (int j = 0; j < 16; ++j) ix[j] = csr[e + j];
        uint32 vv[16];
#pragma unroll
        for (int j = 0; j < 16; ++j) vv[j] = g[(size_t)ix[j] * 64 + lane];
#pragma unroll
        for (int j = 0; j < 16; ++j) { s0 += blo(vv[j]); s1 += bhi(vv[j]); }
    }
    for (; e + 4 <= e1; e += 4) {
        int ix[4];
#pragma unroll
        for (int j = 0; j < 4; ++j) ix[j] = csr[e + j];
        uint32 vv[4];
#pragma unroll
        for (int j = 0; j < 4; ++j) vv[j] = g[(size_t)ix[j] * 64 + lane];
#pragma unroll
        for (int j = 0; j < 4; ++j) { s0 += blo(vv[j]); s1 += bhi(vv[j]); }
    }
    for (; e < e1; ++e) {
        uint32 v = g[(size_t)csr[e] * 64 + lane];
        s0 += blo(v); s1 += bhi(v);
    }
    float dc = dinv[w];
    f32x2 bb = bias[lane];
    float o0 = fmaxf(fmaf(s0, dc, bb[0]), 0.f);
    float o1 = fmaxf(fmaf(s1, dc, bb[1]), 0.f);
    outH[(size_t)w * 64 + lane] = packbf(o0, o1);
}

// ---------- neighbor mean, wave-per-node, 16-unroll, bf16 out ----------
__global__ __launch_bounds__(256) void k_mean(
    const uint32* __restrict__ h, const u16* __restrict__ csr,
    const int* __restrict__ off, const int* __restrict__ endo,
    uint32* __restrict__ outH, int n) {
    int w = (blockIdx.x * 256 + threadIdx.x) >> 6;
    if (w >= n) return;
    int lane = threadIdx.x & 63;
    int e = off[w], e1 = endo[w];
    int d = e1 - e;
    float s0 = 0.f, s1 = 0.f;
    for (; e + 16 <= e1; e += 16) {
        int ix[16];
#pragma unroll
        for (int j = 0; j < 16; ++j) ix[j] = csr[e + j];
        uint32 vv[16];
#pragma unroll
        for (int j = 0; j < 16; ++j) vv[j] = h[(size_t)ix[j] * 64 + lane];
#pragma unroll
        for (int j = 0; j < 16; ++j) { s0 += blo(vv[j]); s1 += bhi(vv[j]); }
    }
    for (; e + 4 <= e1; e += 4) {
        int ix[4];
#pragma unroll
        for (int j = 0; j < 4; ++j) ix[j] = csr[e + j];
        uint32 vv[4];
#pragma unroll
        for (int j = 0; j < 4; ++j) vv[j] = h[(size_t)ix[j] * 64 + lane];
#pragma unroll
        for (int j = 0; j < 4; ++j) { s0 += blo(vv[j]); s1 += bhi(vv[j]); }
    }
    for (; e < e1; ++e) {
        uint32 v = h[(size_t)csr[e] * 64 + lane];
        s0 += blo(v); s1 += bhi(v);
    }
    float o0, o1;
    if (d > 0) {
        float inv = 1.f / (float)d;
        o0 = s0 * inv; o1 = s1 * inv;
    } else {
        uint32 sv = h[(size_t)w * 64 + lane];
        o0 = blo(sv); o1 = bhi(sv);
    }
    outH[(size_t)w * 64 + lane] = packbf(o0, o1);
}

// ---------- final: out = (w0*h0 + w1*h1 + w2*h2) @ fcW + fc_b ----------
__global__ __launch_bounds__(256) void k_final(
    const u16* __restrict__ h0, const u16* __restrict__ h1,
    const u16* __restrict__ h2, const float* __restrict__ jkw,
    const u16* __restrict__ fcWTh, const u16* __restrict__ fcWTl,
    const float* __restrict__ fcb, float* __restrict__ out, int M) {
    float a0 = jkw[0], a1 = jkw[1], a2 = jkw[2];
    float mx = fmaxf(a0, fmaxf(a1, a2));
    float e0 = expf(a0 - mx), e1 = expf(a1 - mx), e2 = expf(a2 - mx);
    float inv = 1.f / (e0 + e1 + e2);
    float w0 = e0 * inv, w1 = e1 * inv, w2 = e2 * inv;

    const int lane = threadIdx.x & 63;
    const int q = lane >> 4, l = lane & 15;
    int rbase = blockIdx.x * 128 + (threadIdx.x >> 6) * 32;
    if (rbase >= M) return;
    int r0 = rbase + l;      if (r0 >= M) r0 = M - 1;
    int r1 = rbase + 16 + l; if (r1 >= M) r1 = M - 1;

    f32x4 acc[2][4];
#pragma unroll
    for (int i = 0; i < 2; ++i)
#pragma unroll
        for (int j = 0; j < 4; ++j) acc[i][j] = (f32x4){0.f, 0.f, 0.f, 0.f};

    union U8 { bfx8 v; u16 u[8]; };

#pragma unroll
    for (int kc = 0; kc < 4; ++kc) {
        int k0 = kc * 32 + q * 8;
        bfx8 ah[2];
        const int rr2[2] = {r0, r1};
#pragma unroll
        for (int half = 0; half < 2; ++half) {
            size_t o = (size_t)rr2[half] * 128 + k0;
            U8 x0, x1, x2, rh;
            x0.v = *(const bfx8*)(h0 + o);
            x1.v = *(const bfx8*)(h1 + o);
            x2.v = *(const bfx8*)(h2 + o);
#pragma unroll
            for (int j = 0; j < 8; ++j) {
                float c = w0 * b2f(x0.u[j]) + w1 * b2f(x1.u[j]) + w2 * b2f(x2.u[j]);
                rh.u[j] = f2b(c);
            }
            ah[half] = rh.v;
        }
#pragma unroll
        for (int ct = 0; ct < 4; ++ct) {
            bfx8 bh = *(const bfx8*)(fcWTh + (ct * 16 + l) * 128 + k0);
            bfx8 bl = *(const bfx8*)(fcWTl + (ct * 16 + l) * 128 + k0);
#pragma unroll
            for (int half = 0; half < 2; ++half) {
                acc[half][ct] = __builtin_amdgcn_mfma_f32_16x16x32_bf16(ah[half], bh, acc[half][ct], 0, 0, 0);
                acc[half][ct] = __builtin_amdgcn_mfma_f32_16x16x32_bf16(ah[half], bl, acc[half][ct], 0, 0, 0);
            }
        }
    }
#pragma unroll
    for (int rs = 0; rs < 2; ++rs) {
#pragma unroll
        for (int rr = 0; rr < 4; ++rr) {
            int rw = rbase + rs * 16 + q * 4 + rr;
            if (rw < M) {
#pragma unroll
                for (int ct = 0; ct < 4; ++ct) {
                    int cc = ct * 16 + l;
                    out[(size_t)rw * 64 + cc] = acc[rs][ct][rr] + fcb[cc];
                }
            }
        }
    }
}

extern "C" void kernel_launch(void* const* d_in, const int* in_sizes, int n_in,
                              void* d_out, int out_size, void* d_ws, size_t ws_size,
                              hipStream_t stream) {
    const int N = in_sizes[0] / 128;   // 50000
    const int E = in_sizes[1] / 2;     // 800000
    const int NB = (N + 255) >> 8;     // 196 buckets

    const float* x    = (const float*)d_in[0];
    const int* row    = (const int*)d_in[1];
    const int* col    = row + E;
    const float* W1   = (const float*)d_in[2];
    const float* b1   = (const float*)d_in[3];
    const float* W2   = (const float*)d_in[4];
    const float* b2   = (const float*)d_in[5];
    const float* W3   = (const float*)d_in[6];
    const float* b3   = (const float*)d_in[7];
    const float* jkw  = (const float*)d_in[8];
    const float* fcW  = (const float*)d_in[9];
    const float* fcb  = (const float*)d_in[10];
    float* outp       = (float*)d_out;

    char* ws = (char*)d_ws;
    size_t off = 0;
    auto alloc = [&](size_t bytes) -> char* {
        char* p = ws + off;
        off += (bytes + 255) & ~(size_t)255;
        return p;
    };
    int* curC   = (int*)alloc((size_t)NBP * sizeof(int));
    int* curR   = (int*)alloc((size_t)NBP * sizeof(int));
    int* off_in  = (int*)alloc((size_t)N * sizeof(int));
    int* end_in  = (int*)alloc((size_t)N * sizeof(int));
    int* off_out = (int*)alloc((size_t)N * sizeof(int));
    int* end_out = (int*)alloc((size_t)N * sizeof(int));
    uint32* partC = (uint32*)alloc((size_t)NBP * BS * sizeof(uint32));
    uint32* partR = (uint32*)alloc((size_t)NBP * BS * sizeof(uint32));
    u16* csr_src = (u16*)alloc((size_t)NBP * BS * sizeof(u16));
    u16* csr_dst = (u16*)alloc((size_t)NBP * BS * sizeof(u16));
    float* dinv  = (float*)alloc((size_t)N * sizeof(float));
    const int WTN = 3 * 16384 + 8192;
    u16* WTh = (u16*)alloc((size_t)WTN * sizeof(u16));
    u16* WTl = (u16*)alloc((size_t)WTN * sizeof(u16));
    size_t FB = (size_t)N * 128 * sizeof(u16);
    u16* gbuf = (u16*)alloc(FB);
    u16* t0   = (u16*)alloc(FB);
    u16* h0   = (u16*)alloc(FB);
    u16* h1   = (u16*)alloc(FB);
    u16* h2   = (u16*)alloc(FB);

    const int B = 256;
    int Gh = (E + CH - 1) / CH;
    int Gg = (N + 127) / 128;
    int Gwt = (WTN + B - 1) / B;

    k_init<<<1 + Gwt, B, 0, stream>>>(curC, curR, W1, W2, W3, fcW, WTh, WTl, WTN);
    k_partC<<<Gh, B, 0, stream>>>(row, col, E, curC, curR, partC, partR);
    k_fillD<<<2 * NB, B, 0, stream>>>(partC, partR, curC, curR,
                                      off_in, end_in, off_out, end_out,
                                      csr_src, csr_dst, dinv, NB, N);
    k_gemm0<<<Gg, B, 0, stream>>>(x, WTh, WTl, dinv, gbuf, N);

    int aggG = (N + 3) / 4;            // 4 waves/block, 1 node/wave

    // layer 0
    k_agg<<<aggG, B, 0, stream>>>((const uint32*)gbuf, csr_src, off_in, end_in, dinv,
                                  (const f32x2*)b1, (uint32*)t0, N);
    k_mean<<<aggG, B, 0, stream>>>((const uint32*)t0, csr_dst, off_out, end_out,
                                   (uint32*)h0, N);
    // layer 1
    k_gemm1p<<<Gg, B, 0, stream>>>(h0, WTh + 16384, WTl + 16384, dinv, gbuf, N);
    k_agg<<<aggG, B, 0, stream>>>((const uint32*)gbuf, csr_src, off_in, end_in, dinv,
                                  (const f32x2*)b2, (uint32*)h1, N);
    // layer 2
    k_gemm1p<<<Gg, B, 0, stream>>>(h1, WTh + 2 * 16384, WTl + 2 * 16384, dinv, gbuf, N);
    k_agg<<<aggG, B, 0, stream>>>((const uint32*)gbuf, csr_src, off_in, end_in, dinv,
                                  (const f32x2*)b3, (uint32*)h2, N);
    // JK combine + final linear
    k_final<<<Gg, B, 0, stream>>>(h0, h1, h2, jkw,
                                  WTh + 3 * 16384, WTl + 3 * 16384, fcb, outp, N);
}